// Round 18
// baseline (111.137 us; speedup 1.0000x reference)
//
#include <hip/hip_runtime.h>

// ---------------------------------------------------------------------------
// SelfAttention: B=4, N=4096 tokens/batch, C=512, DQK=64
// out = gamma * softmax((X Wf)(X Wg)^T) (X Wh) + X
// Round 18: producer/consumer wave role-split — waves 0-3 = S/softmax
// producers (1 qf each), waves 4-7 = pure-MFMA PV consumers (128 cols each,
// staggered per-cf V reload). Same 2-tile 4-buffer P FIFO + lgkm-only
// barrier as R17. 512 thr / 8 waves / 2 per SIMD (1 producer + 1 consumer
// per SIMD via w%4 round-robin) / 1 block/CU.
// ---------------------------------------------------------------------------

typedef __bf16 bf16x8 __attribute__((ext_vector_type(8)));
typedef __bf16 bf16x2 __attribute__((ext_vector_type(2)));
typedef float f32x4 __attribute__((ext_vector_type(4)));
typedef unsigned int u32x4 __attribute__((ext_vector_type(4)));
typedef unsigned int u32;

#define L2E 1.4426950408889634f

__device__ __forceinline__ unsigned short f2bf(float f) {
    unsigned int u = __builtin_bit_cast(unsigned int, f);
    u += 0x7fffu + ((u >> 16) & 1u);   // RNE
    return (unsigned short)(u >> 16);
}
__device__ __forceinline__ u32 cvtpk(float a, float b) {
    bf16x2 t; t[0] = (__bf16)a; t[1] = (__bf16)b;   // -> v_cvt_pk_bf16_f32
    return __builtin_bit_cast(u32, t);
}
__device__ __forceinline__ bf16x8 ld8(const void* p) {
    u32x4 u = *reinterpret_cast<const u32x4*>(p);
    return __builtin_bit_cast(bf16x8, u);
}
__device__ __forceinline__ bf16x8 ldx(const float* p) {
    float4 a = *reinterpret_cast<const float4*>(p);
    float4 b = *reinterpret_cast<const float4*>(p + 4);
    u32x4 r;
    r.x = cvtpk(a.x, a.y); r.y = cvtpk(a.z, a.w);
    r.z = cvtpk(b.x, b.y); r.w = cvtpk(b.z, b.w);
    return __builtin_bit_cast(bf16x8, r);
}
__device__ __forceinline__ f32x4 mfma16(bf16x8 a, bf16x8 b, f32x4 c) {
    return __builtin_amdgcn_mfma_f32_16x16x32_bf16(a, b, c, 0, 0, 0);
}
__device__ __forceinline__ void gl2lds16(const void* g, void* l) {
    __builtin_amdgcn_global_load_lds(
        (const __attribute__((address_space(1))) u32*)g,
        (__attribute__((address_space(3))) u32*)l, 16, 0, 0);
}

// --------------------------- prep kernel -----------------------------------
// W -> staged layout [16 chunks q][4 slots s][640 cols c][8 bf16]:
//   (q,s,c,j) = W^T[c][k=32q+8s+j]; c<64: f (x log2e), c<128: g, else h.
__global__ __launch_bounds__(256) void cvt_w_all(const float* __restrict__ kf,
                                                 const float* __restrict__ kg,
                                                 const float* __restrict__ kh,
                                                 unsigned short* __restrict__ wst) {
    int idx = blockIdx.x * 256 + threadIdx.x;   // 327680 total
    int j = idx & 7;
    int gi = idx >> 3;
    int c = gi % 640;
    int sq = gi / 640;
    int k = (sq >> 2) * 32 + (sq & 3) * 8 + j;
    float v;
    if (c < 64)       v = kf[k * 64 + c] * L2E;
    else if (c < 128) v = kg[k * 64 + (c - 64)];
    else              v = kh[k * 512 + (c - 128)];
    wst[idx] = f2bf(v);
}

// --------------------- fused projection kernel -----------------------------
// Grid dim3(256, 2). W streamed via 2x20KB LDS dbuf (global_load_lds).
// Outputs:
//   fq  [16384][64]  : f rows (Q), row-major bf16
//   kst [4][64t][4jf][2ks][64l][16B] : K A-fragment stream
//   vst [4][64t][32c16][2ks][64l][16B] : V B-fragment stream (sigma j-order)
__global__ __launch_bounds__(256, 2) void proj_k(const float* __restrict__ x,
                                                 const unsigned short* __restrict__ wst,
                                                 unsigned short* __restrict__ fq,
                                                 unsigned short* __restrict__ kst,
                                                 unsigned short* __restrict__ vst) {
    __shared__ __align__(16) unsigned char Wl[2][20480];
    __shared__ unsigned short Tl[64][72];

    int m0 = blockIdx.x * 64;
    int grp = blockIdx.y;
    int tid = threadIdx.x;
    int w = tid >> 6, l = tid & 63, g = l >> 4, i = l & 15;

    const char* wsrc = (const char*)wst + (size_t)w * 10240 + (size_t)grp * 5120 + l * 16;

#pragma unroll
    for (int s5 = 0; s5 < 5; s5++)
        gl2lds16(wsrc + s5 * 1024, &Wl[0][w * 5120 + s5 * 1024]);

    const float* xrow = x + (size_t)(m0 + 16 * w + i) * 512 + g * 8;
    bf16x8 af[16];
#pragma unroll
    for (int k = 0; k < 16; k++) af[k] = ldx(xrow + 32 * k);

    f32x4 acc[5][4];
#pragma unroll
    for (int t = 0; t < 5; t++)
#pragma unroll
        for (int cf = 0; cf < 4; cf++) acc[t][cf] = f32x4{0, 0, 0, 0};

    int rdoff = g * 5120 + i * 16;

#pragma unroll
    for (int q = 0; q < 16; q++) {
        __syncthreads();
        if (q < 15) {
            const char* src = wsrc + (size_t)(q + 1) * 40960;
#pragma unroll
            for (int s5 = 0; s5 < 5; s5++)
                gl2lds16(src + s5 * 1024, &Wl[(q + 1) & 1][w * 5120 + s5 * 1024]);
        }
        const unsigned char* Wb = &Wl[q & 1][0];
        __builtin_amdgcn_s_setprio(1);
#pragma unroll
        for (int t = 0; t < 5; t++)
#pragma unroll
            for (int cf = 0; cf < 4; cf++) {
                bf16x8 bb = ld8(Wb + rdoff + (t * 64 + 16 * cf) * 16);
                acc[t][cf] = mfma16(af[q], bb, acc[t][cf]);
            }
        __builtin_amdgcn_s_setprio(0);
    }

    int batch = m0 >> 12;
    int kt = (m0 & 4095) >> 6;   // KV tile index (this block's 64 tokens)
    unsigned short* kbase = kst + (size_t)batch * 262144 + (size_t)kt * 4096;
    unsigned short* vbase = vst + (size_t)batch * 2097152 + (size_t)kt * 32768;

#pragma unroll
    for (int t = 0; t < 5; t++) {
        if (grp == 0 && t == 0) {
#pragma unroll
            for (int cf = 0; cf < 4; cf++)
#pragma unroll
                for (int r = 0; r < 4; r++)
                    fq[(size_t)(m0 + 16 * w + 4 * g + r) * 64 + t * 64 + 16 * cf + i] =
                        f2bf(acc[t][cf][r]);
        } else {
            __syncthreads();
#pragma unroll
            for (int cf = 0; cf < 4; cf++) {
                ushort4 v4;
                v4.x = f2bf(acc[t][cf][0]); v4.y = f2bf(acc[t][cf][1]);
                v4.z = f2bf(acc[t][cf][2]); v4.w = f2bf(acc[t][cf][3]);
                *reinterpret_cast<ushort4*>(&Tl[16 * cf + i][16 * w + 4 * g]) = v4;
            }
            __syncthreads();
            if (grp == 0 && t == 1) {
                // g tile -> K fragment stream
#pragma unroll
                for (int ch = tid; ch < 512; ch += 256) {
                    int jf2 = ch >> 7, ks = (ch >> 6) & 1, l2 = ch & 63;
                    int g2 = l2 >> 4, i2 = l2 & 15;
                    ushort4 o0, o1;
                    o0.x = Tl[ks * 32 + 8 * g2 + 0][16 * jf2 + i2];
                    o0.y = Tl[ks * 32 + 8 * g2 + 1][16 * jf2 + i2];
                    o0.z = Tl[ks * 32 + 8 * g2 + 2][16 * jf2 + i2];
                    o0.w = Tl[ks * 32 + 8 * g2 + 3][16 * jf2 + i2];
                    o1.x = Tl[ks * 32 + 8 * g2 + 4][16 * jf2 + i2];
                    o1.y = Tl[ks * 32 + 8 * g2 + 5][16 * jf2 + i2];
                    o1.z = Tl[ks * 32 + 8 * g2 + 6][16 * jf2 + i2];
                    o1.w = Tl[ks * 32 + 8 * g2 + 7][16 * jf2 + i2];
                    unsigned short* dst = kbase + (size_t)(jf2 * 1024 + ks * 512 + l2 * 8);
                    *reinterpret_cast<ushort4*>(dst)     = o0;
                    *reinterpret_cast<ushort4*>(dst + 4) = o1;
                }
            } else {
                // V tile -> B fragment stream (sigma j-order)
                int n0 = (grp == 0) ? (t - 2) * 64 : 192 + t * 64;
#pragma unroll
                for (int ch = tid; ch < 512; ch += 256) {
                    int cc = ch >> 7, ks = (ch >> 6) & 1, l2 = ch & 63;
                    int g2 = l2 >> 4, i2 = l2 & 15;
                    int row = cc * 16 + i2;
                    int jb = 32 * ks + 4 * g2;
                    ushort4 o0, o1;
                    o0.x = Tl[row][jb + 0];  o0.y = Tl[row][jb + 1];
                    o0.z = Tl[row][jb + 2];  o0.w = Tl[row][jb + 3];
                    o1.x = Tl[row][jb + 16]; o1.y = Tl[row][jb + 17];
                    o1.z = Tl[row][jb + 18]; o1.w = Tl[row][jb + 19];
                    int c16 = (n0 >> 4) + cc;
                    unsigned short* dst = vbase + (size_t)(c16 * 1024 + ks * 512 + l2 * 8);
                    *reinterpret_cast<ushort4*>(dst)     = o0;
                    *reinterpret_cast<ushort4*>(dst + 4) = o1;
                }
            }
        }
    }
}

// --------------------------- shared-P attention ----------------------------
// Grid 256 = 4 batch x 64 q-tiles(64 rows); block 512 thr / 8 waves, 1/CU.
// Role split: waves 0-3 = S/softmax producers (qf = w, all jf); waves 4-7 =
// PV consumers (cols 128*(w-4), all qf, staggered per-cf V reload).
// 2-tile iteration, 4-buffer P FIFO, lgkm-only barrier (vmcnt in flight).
__global__ __launch_bounds__(512, 2) void attn_k(const unsigned short* __restrict__ fq,
                                                 const unsigned short* __restrict__ kst,
                                                 const unsigned short* __restrict__ vst,
                                                 const float* __restrict__ x,
                                                 const float* __restrict__ gamma,
                                                 float* __restrict__ out) {
    __shared__ __align__(16) unsigned char Pl[4][8192];   // [buf][qf][ks][64l][16B]
    __shared__ float l_lds[64];

    int bid = blockIdx.x;
    int xcd = bid & 7;
    int batch = xcd >> 1;                       // 2 XCDs per batch
    int qidx = ((xcd & 1) << 5) | (bid >> 3);   // 0..63
    int q0 = qidx * 64;

    int tid = threadIdx.x;
    int w = tid >> 6, l = tid & 63, g = l >> 4, i = l & 15;

    const unsigned short* fqb = fq + (size_t)batch * 4096 * 64;
    const char* kb = (const char*)kst + (size_t)batch * 524288;
    const char* vb = (const char*)vst + (size_t)batch * 4194304;

    if (w < 4) {
        // =============== S/softmax producer: qf = w, all 4 jf ===============
        int qf = w;
        bf16x8 aQ[2];
#pragma unroll
        for (int ks = 0; ks < 2; ks++)
            aQ[ks] = ld8(fqb + (size_t)(q0 + 16 * qf + i) * 64 + ks * 32 + g * 8);

        bf16x8 kAa[4][2], kAb[4][2];
#pragma unroll
        for (int jf = 0; jf < 4; jf++)
#pragma unroll
            for (int ks = 0; ks < 2; ks++) {
                kAa[jf][ks] = ld8(kb + (size_t)(0 * 4 + jf) * 2048 + ks * 1024 + l * 16);
                kAb[jf][ks] = ld8(kb + (size_t)(1 * 4 + jf) * 2048 + ks * 1024 + l * 16);
            }

        float lp = 0.0f;
        // per-jf write offsets into a P buffer
        int pw[4];
#pragma unroll
        for (int jf = 0; jf < 4; jf++)
            pw[jf] = (qf * 2 + (jf >> 1)) * 1024 + l * 16 + (jf & 1) * 8;

        // prologue: S(0),S(1) -> P pair 0; prefetch K(2),K(3)
        {
            f32x4 s0[4], s1[4];
#pragma unroll
            for (int jf = 0; jf < 4; jf++) { s0[jf] = f32x4{0,0,0,0}; s1[jf] = f32x4{0,0,0,0}; }
#pragma unroll
            for (int jf = 0; jf < 4; jf++) {
                s0[jf] = mfma16(kAa[jf][0], aQ[0], s0[jf]);
                s0[jf] = mfma16(kAa[jf][1], aQ[1], s0[jf]);
                s1[jf] = mfma16(kAb[jf][0], aQ[0], s1[jf]);
                s1[jf] = mfma16(kAb[jf][1], aQ[1], s1[jf]);
            }
#pragma unroll
            for (int jf = 0; jf < 4; jf++)
#pragma unroll
                for (int ks = 0; ks < 2; ks++) {
                    kAa[jf][ks] = ld8(kb + (size_t)(2 * 4 + jf) * 2048 + ks * 1024 + l * 16);
                    kAb[jf][ks] = ld8(kb + (size_t)(3 * 4 + jf) * 2048 + ks * 1024 + l * 16);
                }
#pragma unroll
            for (int jf = 0; jf < 4; jf++) {
                float p0 = __builtin_amdgcn_exp2f(s0[jf][0]);
                float p1 = __builtin_amdgcn_exp2f(s0[jf][1]);
                float p2 = __builtin_amdgcn_exp2f(s0[jf][2]);
                float p3 = __builtin_amdgcn_exp2f(s0[jf][3]);
                lp += (p0 + p1) + (p2 + p3);
                uint2 pk2; pk2.x = cvtpk(p0, p1); pk2.y = cvtpk(p2, p3);
                *reinterpret_cast<uint2*>(&Pl[0][0] + pw[jf]) = pk2;
                p0 = __builtin_amdgcn_exp2f(s1[jf][0]);
                p1 = __builtin_amdgcn_exp2f(s1[jf][1]);
                p2 = __builtin_amdgcn_exp2f(s1[jf][2]);
                p3 = __builtin_amdgcn_exp2f(s1[jf][3]);
                lp += (p0 + p1) + (p2 + p3);
                pk2.x = cvtpk(p0, p1); pk2.y = cvtpk(p2, p3);
                *reinterpret_cast<uint2*>(&Pl[1][0] + pw[jf]) = pk2;
            }
        }

        for (int u = 0; u < 32; ++u) {
            asm volatile("s_waitcnt lgkmcnt(0)" ::: "memory");
            __builtin_amdgcn_s_barrier();

            // S(2u+2), S(2u+3)
            f32x4 s0[4], s1[4];
#pragma unroll
            for (int jf = 0; jf < 4; jf++) { s0[jf] = f32x4{0,0,0,0}; s1[jf] = f32x4{0,0,0,0}; }
#pragma unroll
            for (int jf = 0; jf < 4; jf++) {
                s0[jf] = mfma16(kAa[jf][0], aQ[0], s0[jf]);
                s0[jf] = mfma16(kAa[jf][1], aQ[1], s0[jf]);
                s1[jf] = mfma16(kAb[jf][0], aQ[0], s1[jf]);
                s1[jf] = mfma16(kAb[jf][1], aQ[1], s1[jf]);
            }

            // K(2u+4), K(2u+5) prefetch
            {
                int ta = (2 * u + 4) & 63, tb = (2 * u + 5) & 63;
#pragma unroll
                for (int jf = 0; jf < 4; jf++)
#pragma unroll
                    for (int ks = 0; ks < 2; ks++) {
                        kAa[jf][ks] = ld8(kb + (size_t)(ta * 4 + jf) * 2048 + ks * 1024 + l * 16);
                        kAb[jf][ks] = ld8(kb + (size_t)(tb * 4 + jf) * 2048 + ks * 1024 + l * 16);
                    }
            }

            // P(2u+2),P(2u+3) = exp2(S), pack, write pair (u+1)&1
            float msk = (u < 31) ? 1.0f : 0.0f;
            unsigned char* Pw0 = &Pl[((u + 1) & 1) * 2][0];
            unsigned char* Pw1 = Pw0 + 8192;
#pragma unroll
            for (int jf = 0; jf < 4; jf++) {
                float p0 = __builtin_amdgcn_exp2f(s0[jf][0]);
                float p1 = __builtin_amdgcn_exp2f(s0[jf][1]);
                float p2 = __builtin_amdgcn_exp2f(s0[jf][2]);
                float p3 = __builtin_amdgcn_exp2f(s0[jf][3]);
                lp += msk * ((p0 + p1) + (p2 + p3));
                uint2 pk2; pk2.x = cvtpk(p0, p1); pk2.y = cvtpk(p2, p3);
                *reinterpret_cast<uint2*>(Pw0 + pw[jf]) = pk2;
                p0 = __builtin_amdgcn_exp2f(s1[jf][0]);
                p1 = __builtin_amdgcn_exp2f(s1[jf][1]);
                p2 = __builtin_amdgcn_exp2f(s1[jf][2]);
                p3 = __builtin_amdgcn_exp2f(s1[jf][3]);
                lp += msk * ((p0 + p1) + (p2 + p3));
                pk2.x = cvtpk(p0, p1); pk2.y = cvtpk(p2, p3);
                *reinterpret_cast<uint2*>(Pw1 + pw[jf]) = pk2;
            }
        }

        // l reduction over g; direct store (each qf owned by one wave)
        lp += __shfl_xor(lp, 16, 64);
        lp += __shfl_xor(lp, 32, 64);
        if (g == 0) l_lds[16 * qf + i] = lp;
        __syncthreads();
        // producers done (no output duty)
    } else {
        // =============== PV consumer: cols 128*(w-4), all 4 qf ==============
        int p = w - 4;
        int c16b = 8 * p;   // column-16 base

        bf16x8 vbr[8][2];
#pragma unroll
        for (int cf = 0; cf < 8; cf++)
#pragma unroll
            for (int ks = 0; ks < 2; ks++)
                vbr[cf][ks] = ld8(vb + (size_t)(c16b + cf) * 2048 + ks * 1024 + l * 16);

        f32x4 acc[4][8];
#pragma unroll
        for (int a = 0; a < 4; a++)
#pragma unroll
            for (int b = 0; b < 8; b++) acc[a][b] = f32x4{0, 0, 0, 0};

        for (int u = 0; u < 32; ++u) {
            asm volatile("s_waitcnt lgkmcnt(0)" ::: "memory");
            __builtin_amdgcn_s_barrier();

            const unsigned char* Pr0 = &Pl[(u & 1) * 2][0];
            const unsigned char* Pr1 = Pr0 + 8192;

            // ---- tile 2u: P read + 32 MFMA; staggered vbr<-V(2u+1) ----
            {
                bf16x8 aP[4][2];
#pragma unroll
                for (int qf = 0; qf < 4; qf++)
#pragma unroll
                    for (int ks = 0; ks < 2; ks++)
                        aP[qf][ks] = ld8(Pr0 + (qf * 2 + ks) * 1024 + l * 16);
                int tv = (2 * u + 1) & 63;
                __builtin_amdgcn_s_setprio(1);
#pragma unroll
                for (int cf = 0; cf < 8; cf++) {
#pragma unroll
                    for (int qf = 0; qf < 4; qf++) {
                        acc[qf][cf] = mfma16(aP[qf][0], vbr[cf][0], acc[qf][cf]);
                        acc[qf][cf] = mfma16(aP[qf][1], vbr[cf][1], acc[qf][cf]);
                    }
#pragma unroll
                    for (int ks = 0; ks < 2; ks++)
                        vbr[cf][ks] = ld8(vb + (size_t)(tv * 32 + c16b + cf) * 2048 +
                                          ks * 1024 + l * 16);
                }
                __builtin_amdgcn_s_setprio(0);
            }

            // ---- tile 2u+1: P read + 32 MFMA; staggered vbr<-V(2u+2) ----
            {
                bf16x8 aP[4][2];
#pragma unroll
                for (int qf = 0; qf < 4; qf++)
#pragma unroll
                    for (int ks = 0; ks < 2; ks++)
                        aP[qf][ks] = ld8(Pr1 + (qf * 2 + ks) * 1024 + l * 16);
                int tv = (2 * u + 2) & 63;
                __builtin_amdgcn_s_setprio(1);
#pragma unroll
                for (int cf = 0; cf < 8; cf++) {
#pragma unroll
                    for (int qf = 0; qf < 4; qf++) {
                        acc[qf][cf] = mfma16(aP[qf][0], vbr[cf][0], acc[qf][cf]);
                        acc[qf][cf] = mfma16(aP[qf][1], vbr[cf][1], acc[qf][cf]);
                    }
#pragma unroll
                    for (int ks = 0; ks < 2; ks++)
                        vbr[cf][ks] = ld8(vb + (size_t)(tv * 32 + c16b + cf) * 2048 +
                                          ks * 1024 + l * 16);
                }
                __builtin_amdgcn_s_setprio(0);
            }
        }

        __syncthreads();   // l_lds ready

        // ---- epilogue: out = gamma*O/l + x (cols 128p..128p+127) ----
        float gam = gamma[0];
#pragma unroll
        for (int qf = 0; qf < 4; qf++) {
#pragma unroll
            for (int r = 0; r < 4; r++) {
                float linv = gam / l_lds[16 * qf + 4 * g + r];
                int n = q0 + 16 * qf + 4 * g + r;
                size_t base = ((size_t)batch * 4096 + n) * 512 + 128 * p;
#pragma unroll
                for (int cf = 0; cf < 8; cf++)
                    out[base + 16 * cf + i] = acc[qf][cf][r] * linv + x[base + 16 * cf + i];
            }
        }
    }
}

// --------------------------- launcher --------------------------------------

extern "C" void kernel_launch(void* const* d_in, const int* in_sizes, int n_in,
                              void* d_out, int out_size, void* d_ws, size_t ws_size,
                              hipStream_t stream) {
    const float* x = (const float*)d_in[0];
    const float* kf = (const float*)d_in[1];
    const float* kg = (const float*)d_in[2];
    const float* kh = (const float*)d_in[3];
    const float* gamma = (const float*)d_in[4];
    float* out = (float*)d_out;

    char* ws = (char*)d_ws;
    unsigned short* Fq  = (unsigned short*)(ws);               // 2 MB
    unsigned short* Kst = (unsigned short*)(ws + 2097152);     // 2 MB
    unsigned short* Vst = (unsigned short*)(ws + 4194304);     // 16 MB
    unsigned short* Wst = (unsigned short*)(ws + 20971520);    // 640 KB

    cvt_w_all<<<1280, 256, 0, stream>>>(kf, kg, kh, Wst);
    proj_k<<<dim3(256, 2), 256, 0, stream>>>(x, Wst, Fq, Kst, Vst);
    attn_k<<<256, 512, 0, stream>>>(Fq, Kst, Vst, x, gamma, out);
}